// Round 1
// baseline (194.999 us; speedup 1.0000x reference)
//
#include <hip/hip_runtime.h>
#include <hip/hip_bf16.h>

#define B_ 4
#define T_ 2048
#define E_ 1024
#define H_ 16
#define D_ 64
#define Mtot 8192
#define N2 2048
#define K_ 1024

typedef __attribute__((ext_vector_type(8))) short short8;
typedef __attribute__((ext_vector_type(4))) float f32x4;
using bf16 = __hip_bfloat16;

// ---------------- cast fp32 -> bf16 (vectorized) ----------------
__global__ void cast_f32_to_bf16(const float* __restrict__ in, ushort* __restrict__ out, int n4) {
  int stride = gridDim.x * blockDim.x;
  for (int i = blockIdx.x * blockDim.x + threadIdx.x; i < n4; i += stride) {
    float4 v = reinterpret_cast<const float4*>(in)[i];
    bf16 a = __float2bfloat16(v.x), b = __float2bfloat16(v.y);
    bf16 c = __float2bfloat16(v.z), d = __float2bfloat16(v.w);
    ushort4 o = make_ushort4(*(ushort*)&a, *(ushort*)&b, *(ushort*)&c, *(ushort*)&d);
    reinterpret_cast<ushort4*>(out)[i] = o;
  }
}

// ---------------- lift GEMM: C[m][f] = sum_e g[m][e] * Wl[f][e] ----------------
// A [8192][1024] bf16 row-major, Bm [2048][1024] bf16 row-major (B^T form).
// 128x128 tile, BK=32, 4 waves each 64x64. Output scattered to qh/kh [b][h][t][d] bf16.
#define BM 128
#define BN 128
#define BK 32
#define APAD 40  // 32 + 8 pad (80B row stride -> conflict-friendly)

__launch_bounds__(256)
__global__ void lift_gemm(const bf16* __restrict__ A, const bf16* __restrict__ Bm,
                          bf16* __restrict__ qh, bf16* __restrict__ kh) {
  __shared__ __align__(16) bf16 sA[BM * APAD];
  __shared__ __align__(16) bf16 sB[BN * APAD];
  const int m0 = blockIdx.x * BM;
  const int n0 = blockIdx.y * BN;
  const int tid = threadIdx.x;
  const int lane = tid & 63, w = tid >> 6;
  const int wr = w >> 1, wc = w & 1;
  const int lr = lane & 15, lg = lane >> 4;

  f32x4 acc[4][4];
#pragma unroll
  for (int i = 0; i < 4; ++i)
#pragma unroll
    for (int j = 0; j < 4; ++j) acc[i][j] = (f32x4)(0.0f);

  for (int k0 = 0; k0 < K_; k0 += BK) {
    __syncthreads();
    // stage A and B tiles: 128x32 each = 512 chunks of 8 bf16
#pragma unroll
    for (int it = 0; it < 2; ++it) {
      int ci = it * 256 + tid;
      int r = ci >> 2, c = (ci & 3) << 3;
      *(float4*)&sA[r * APAD + c] = *(const float4*)&A[(size_t)(m0 + r) * K_ + k0 + c];
      *(float4*)&sB[r * APAD + c] = *(const float4*)&Bm[(size_t)(n0 + r) * K_ + k0 + c];
    }
    __syncthreads();

    short8 af[4], bf[4];
#pragma unroll
    for (int i = 0; i < 4; ++i)
      af[i] = *(const short8*)&sA[(wr * 64 + i * 16 + lr) * APAD + lg * 8];
#pragma unroll
    for (int j = 0; j < 4; ++j)
      bf[j] = *(const short8*)&sB[(wc * 64 + j * 16 + lr) * APAD + lg * 8];
#pragma unroll
    for (int i = 0; i < 4; ++i)
#pragma unroll
      for (int j = 0; j < 4; ++j)
        acc[i][j] = __builtin_amdgcn_mfma_f32_16x16x32_bf16(af[i], bf[j], acc[i][j], 0, 0, 0);
  }

  // epilogue: scatter bf16 into qh/kh [b][h][t][d]
#pragma unroll
  for (int i = 0; i < 4; ++i) {
#pragma unroll
    for (int j = 0; j < 4; ++j) {
#pragma unroll
      for (int r = 0; r < 4; ++r) {
        int m = m0 + wr * 64 + i * 16 + lg * 4 + r;
        int f = n0 + wc * 64 + j * 16 + lr;
        bf16 bv = __float2bfloat16(acc[i][j][r]);
        int b = m >> 11, t = m & (T_ - 1);
        int hh = (f & (E_ - 1)) >> 6, d = f & (D_ - 1);
        bf16* dst = (f < E_) ? qh : kh;
        dst[((((size_t)b * H_ + hh) * T_) + t) * D_ + d] = bv;
      }
    }
  }
}

// ---------------- causal LSE (flash-style, no V) ----------------
// grid (B*H, T/64). 4 waves, each owns 16 q-rows. K-tiles of 64 staged in LDS.
#define QT 64
#define KT 64
#define KPAD 72

__launch_bounds__(256)
__global__ void attn_lse(const bf16* __restrict__ qh, const bf16* __restrict__ kh,
                         float* __restrict__ lse) {
  __shared__ __align__(16) bf16 sK[KT * KPAD];
  const int bh = blockIdx.x;
  const int qt = blockIdx.y;
  const int tid = threadIdx.x;
  const int lane = tid & 63, w = tid >> 6;
  const int lr = lane & 15, lg = lane >> 4;
  const int qbase = qt * QT + w * 16;

  const bf16* qp = qh + ((size_t)bh * T_ + qbase) * D_;
  short8 qf0 = *(const short8*)&qp[lr * D_ + lg * 8];
  short8 qf1 = *(const short8*)&qp[lr * D_ + 32 + lg * 8];

  float mrun[4], lrun[4];
#pragma unroll
  for (int r = 0; r < 4; ++r) { mrun[r] = -INFINITY; lrun[r] = 0.0f; }

  for (int kt = 0; kt <= qt; ++kt) {
    __syncthreads();
#pragma unroll
    for (int it = 0; it < 2; ++it) {
      int ci = it * 256 + tid;
      int r = ci >> 3, c = (ci & 7) << 3;
      *(float4*)&sK[r * KPAD + c] =
          *(const float4*)&kh[((size_t)bh * T_ + kt * KT + r) * D_ + c];
    }
    __syncthreads();

    if (kt * KT <= qbase + 15) {
      f32x4 s[4];
#pragma unroll
      for (int j = 0; j < 4; ++j) s[j] = (f32x4)(0.0f);
#pragma unroll
      for (int j = 0; j < 4; ++j) {
        short8 kf0 = *(const short8*)&sK[(j * 16 + lr) * KPAD + lg * 8];
        s[j] = __builtin_amdgcn_mfma_f32_16x16x32_bf16(qf0, kf0, s[j], 0, 0, 0);
        short8 kf1 = *(const short8*)&sK[(j * 16 + lr) * KPAD + 32 + lg * 8];
        s[j] = __builtin_amdgcn_mfma_f32_16x16x32_bf16(qf1, kf1, s[j], 0, 0, 0);
      }
      // online max / sum-exp per row (4 rows per lane, reg r)
#pragma unroll
      for (int r = 0; r < 4; ++r) {
        int qrow = qbase + lg * 4 + r;
        float sv[4];
        float tm = -INFINITY;
#pragma unroll
        for (int j = 0; j < 4; ++j) {
          int key = kt * KT + j * 16 + lr;
          float v = s[j][r];
          if (key > qrow) v = -INFINITY;
          sv[j] = v;
          tm = fmaxf(tm, v);
        }
#pragma unroll
        for (int off = 1; off < 16; off <<= 1) tm = fmaxf(tm, __shfl_xor(tm, off));
        float mnew = fmaxf(mrun[r], tm);
        float ps = 0.0f;
#pragma unroll
        for (int j = 0; j < 4; ++j)
          ps += (sv[j] == -INFINITY) ? 0.0f : expf(sv[j] - mnew);
#pragma unroll
        for (int off = 1; off < 16; off <<= 1) ps += __shfl_xor(ps, off);
        lrun[r] = lrun[r] * expf(mrun[r] - mnew) + ps;
        mrun[r] = mnew;
      }
    }
  }

  if (lr == 0) {
#pragma unroll
    for (int r = 0; r < 4; ++r) {
      lse[(size_t)bh * T_ + qbase + lg * 4 + r] = mrun[r] + logf(lrun[r]);
    }
  }
}

// ---------------- final: out[b,t] = sum_h lse[b,h,t] * cw[h] ----------------
__global__ void proj_out(const float* __restrict__ lse, const float* __restrict__ Wp,
                         float* __restrict__ out) {
  __shared__ float cw[H_];
  int tid = threadIdx.x;
  if (tid < H_) {
    float s = 0.0f;
    for (int g = 0; g < H_; ++g) s += Wp[g * H_ + tid];
    cw[tid] = s;
  }
  __syncthreads();
  int idx = blockIdx.x * blockDim.x + tid;  // b*T + t
  int b = idx >> 11, t = idx & (T_ - 1);
  float s = 0.0f;
#pragma unroll
  for (int h = 0; h < H_; ++h) s += lse[((size_t)(b * H_ + h) * T_) + t] * cw[h];
  out[idx] = s;
}

// ---------------- launch ----------------
extern "C" void kernel_launch(void* const* d_in, const int* in_sizes, int n_in,
                              void* d_out, int out_size, void* d_ws, size_t ws_size,
                              hipStream_t stream) {
  (void)in_sizes; (void)n_in; (void)out_size; (void)ws_size;
  const float* g  = (const float*)d_in[0];   // [B,T,E] fp32
  const float* Wl = (const float*)d_in[1];   // [2E,E] fp32
  const float* Wp = (const float*)d_in[2];   // [H,H] fp32
  float* out = (float*)d_out;                // [B*T] fp32

  char* ws = (char*)d_ws;
  size_t off = 0;
  bf16* g_bf  = (bf16*)(ws + off); off += (size_t)Mtot * K_ * 2;   // 16 MB
  bf16* wl_bf = (bf16*)(ws + off); off += (size_t)N2 * K_ * 2;     // 4 MB
  bf16* qh    = (bf16*)(ws + off); off += (size_t)B_ * H_ * T_ * D_ * 2;  // 16 MB
  bf16* kh    = (bf16*)(ws + off); off += (size_t)B_ * H_ * T_ * D_ * 2;  // 16 MB
  float* lse  = (float*)(ws + off);                                // 0.5 MB

  // casts
  cast_f32_to_bf16<<<2048, 256, 0, stream>>>(g,  (ushort*)g_bf,  (Mtot * K_) / 4);
  cast_f32_to_bf16<<<512,  256, 0, stream>>>(Wl, (ushort*)wl_bf, (N2 * K_) / 4);

  // lift GEMM -> q/k heads
  lift_gemm<<<dim3(Mtot / BM, N2 / BN), 256, 0, stream>>>(g_bf, wl_bf, qh, kh);

  // causal LSE
  attn_lse<<<dim3(B_ * H_, T_ / QT), 256, 0, stream>>>(qh, kh, lse);

  // final projection
  proj_out<<<(B_ * T_) / 256, 256, 0, stream>>>(lse, Wp, out);
}

// Round 2
// 144.607 us; speedup vs baseline: 1.3485x; 1.3485x over previous
//
#include <hip/hip_runtime.h>
#include <hip/hip_bf16.h>

#define B_ 4
#define T_ 2048
#define E_ 1024
#define H_ 16
#define D_ 64
#define Mtot 8192
#define N2 2048
#define K_ 1024

typedef __attribute__((ext_vector_type(8))) short short8;
typedef __attribute__((ext_vector_type(4))) float f32x4;
using bf16 = __hip_bfloat16;

// ---------------- cast fp32 -> bf16 (vectorized) ----------------
__global__ void cast_f32_to_bf16(const float* __restrict__ in, ushort* __restrict__ out, int n4) {
  int stride = gridDim.x * blockDim.x;
  for (int i = blockIdx.x * blockDim.x + threadIdx.x; i < n4; i += stride) {
    float4 v = reinterpret_cast<const float4*>(in)[i];
    bf16 a = __float2bfloat16(v.x), b = __float2bfloat16(v.y);
    bf16 c = __float2bfloat16(v.z), d = __float2bfloat16(v.w);
    ushort4 o = make_ushort4(*(ushort*)&a, *(ushort*)&b, *(ushort*)&c, *(ushort*)&d);
    reinterpret_cast<ushort4*>(out)[i] = o;
  }
}

// ---------------- lift GEMM: C[m][f] = sum_e g[m][e] * Wl[f][e] ----------------
#define BM 128
#define BN 128
#define BK 32
#define APAD 40

__launch_bounds__(256)
__global__ void lift_gemm(const bf16* __restrict__ A, const bf16* __restrict__ Bm,
                          bf16* __restrict__ qh, bf16* __restrict__ kh) {
  __shared__ __align__(16) bf16 sA[BM * APAD];
  __shared__ __align__(16) bf16 sB[BN * APAD];
  const int m0 = blockIdx.x * BM;
  const int n0 = blockIdx.y * BN;
  const int tid = threadIdx.x;
  const int lane = tid & 63, w = tid >> 6;
  const int wr = w >> 1, wc = w & 1;
  const int lr = lane & 15, lg = lane >> 4;

  f32x4 acc[4][4];
#pragma unroll
  for (int i = 0; i < 4; ++i)
#pragma unroll
    for (int j = 0; j < 4; ++j) acc[i][j] = (f32x4)(0.0f);

  for (int k0 = 0; k0 < K_; k0 += BK) {
    __syncthreads();
#pragma unroll
    for (int it = 0; it < 2; ++it) {
      int ci = it * 256 + tid;
      int r = ci >> 2, c = (ci & 3) << 3;
      *(float4*)&sA[r * APAD + c] = *(const float4*)&A[(size_t)(m0 + r) * K_ + k0 + c];
      *(float4*)&sB[r * APAD + c] = *(const float4*)&Bm[(size_t)(n0 + r) * K_ + k0 + c];
    }
    __syncthreads();

    short8 af[4], bf[4];
#pragma unroll
    for (int i = 0; i < 4; ++i)
      af[i] = *(const short8*)&sA[(wr * 64 + i * 16 + lr) * APAD + lg * 8];
#pragma unroll
    for (int j = 0; j < 4; ++j)
      bf[j] = *(const short8*)&sB[(wc * 64 + j * 16 + lr) * APAD + lg * 8];
#pragma unroll
    for (int i = 0; i < 4; ++i)
#pragma unroll
      for (int j = 0; j < 4; ++j)
        acc[i][j] = __builtin_amdgcn_mfma_f32_16x16x32_bf16(af[i], bf[j], acc[i][j], 0, 0, 0);
  }

#pragma unroll
  for (int i = 0; i < 4; ++i) {
#pragma unroll
    for (int j = 0; j < 4; ++j) {
#pragma unroll
      for (int r = 0; r < 4; ++r) {
        int m = m0 + wr * 64 + i * 16 + lg * 4 + r;
        int f = n0 + wc * 64 + j * 16 + lr;
        bf16 bv = __float2bfloat16(acc[i][j][r]);
        int b = m >> 11, t = m & (T_ - 1);
        int hh = (f & (E_ - 1)) >> 6, d = f & (D_ - 1);
        bf16* dst = (f < E_) ? qh : kh;
        dst[((((size_t)b * H_ + hh) * T_) + t) * D_ + d] = bv;
      }
    }
  }
}

// ---------------- causal LSE: no-max sum-exp, per-lane accumulation ----------------
// grid (B*H, 16). Block = 4 waves; wave w owns 32 q rows [qt*128 + w*32, +32).
// No LDS, no barriers: each wave streams K fragments from global (L2/L3-resident).
#define LSE_QT 128

__launch_bounds__(256)
__global__ void attn_lse(const bf16* __restrict__ qh, const bf16* __restrict__ kh,
                         float* __restrict__ lse) {
  const int bh = blockIdx.x;
  const int qt = (gridDim.y - 1) - blockIdx.y;  // heavy blocks first
  const int tid = threadIdx.x;
  const int lane = tid & 63, w = tid >> 6;
  const int lr = lane & 15, lg = lane >> 4;
  const int qbase = qt * LSE_QT + w * 32;

  // Q fragments: 2 row-frags x 2 k-halves
  const bf16* qp = qh + ((size_t)bh * T_ + qbase) * D_;
  short8 qf[2][2];
#pragma unroll
  for (int f = 0; f < 2; ++f)
#pragma unroll
    for (int h = 0; h < 2; ++h)
      qf[f][h] = *(const short8*)&qp[(size_t)(f * 16 + lr) * D_ + h * 32 + lg * 8];

  float l[2][4];
#pragma unroll
  for (int f = 0; f < 2; ++f)
#pragma unroll
    for (int r = 0; r < 4; ++r) l[f][r] = 0.0f;

  const bf16* kbase = kh + (size_t)bh * T_ * D_;
  const int nfull = qbase >> 6;  // tiles 0..nfull-1 fully unmasked; tile nfull partial

  for (int kt = 0; kt < nfull; ++kt) {
    const bf16* kp = kbase + (size_t)kt * 64 * D_;
    f32x4 s[2][4];
#pragma unroll
    for (int f = 0; f < 2; ++f)
#pragma unroll
      for (int j = 0; j < 4; ++j) s[f][j] = (f32x4)(0.0f);
#pragma unroll
    for (int j = 0; j < 4; ++j) {
      short8 k0 = *(const short8*)&kp[(size_t)(j * 16 + lr) * D_ + lg * 8];
      short8 k1 = *(const short8*)&kp[(size_t)(j * 16 + lr) * D_ + 32 + lg * 8];
      s[0][j] = __builtin_amdgcn_mfma_f32_16x16x32_bf16(qf[0][0], k0, s[0][j], 0, 0, 0);
      s[0][j] = __builtin_amdgcn_mfma_f32_16x16x32_bf16(qf[0][1], k1, s[0][j], 0, 0, 0);
      s[1][j] = __builtin_amdgcn_mfma_f32_16x16x32_bf16(qf[1][0], k0, s[1][j], 0, 0, 0);
      s[1][j] = __builtin_amdgcn_mfma_f32_16x16x32_bf16(qf[1][1], k1, s[1][j], 0, 0, 0);
    }
#pragma unroll
    for (int f = 0; f < 2; ++f)
#pragma unroll
      for (int j = 0; j < 4; ++j)
#pragma unroll
        for (int r = 0; r < 4; ++r) l[f][r] += __expf(s[f][j][r]);
  }

  // diagonal (partial) tile
  {
    const int kt = nfull;
    const bf16* kp = kbase + (size_t)kt * 64 * D_;
    f32x4 s[2][4];
#pragma unroll
    for (int f = 0; f < 2; ++f)
#pragma unroll
      for (int j = 0; j < 4; ++j) s[f][j] = (f32x4)(0.0f);
#pragma unroll
    for (int j = 0; j < 4; ++j) {
      short8 k0 = *(const short8*)&kp[(size_t)(j * 16 + lr) * D_ + lg * 8];
      short8 k1 = *(const short8*)&kp[(size_t)(j * 16 + lr) * D_ + 32 + lg * 8];
      s[0][j] = __builtin_amdgcn_mfma_f32_16x16x32_bf16(qf[0][0], k0, s[0][j], 0, 0, 0);
      s[0][j] = __builtin_amdgcn_mfma_f32_16x16x32_bf16(qf[0][1], k1, s[0][j], 0, 0, 0);
      s[1][j] = __builtin_amdgcn_mfma_f32_16x16x32_bf16(qf[1][0], k0, s[1][j], 0, 0, 0);
      s[1][j] = __builtin_amdgcn_mfma_f32_16x16x32_bf16(qf[1][1], k1, s[1][j], 0, 0, 0);
    }
#pragma unroll
    for (int f = 0; f < 2; ++f)
#pragma unroll
      for (int j = 0; j < 4; ++j)
#pragma unroll
        for (int r = 0; r < 4; ++r) {
          int qrow = qbase + f * 16 + lg * 4 + r;
          int key = kt * 64 + j * 16 + lr;
          float a = (key <= qrow) ? s[f][j][r] : -INFINITY;
          l[f][r] += __expf(a);  // __expf(-inf) == 0
        }
  }

  // cross-lane (lr) reduce and store
#pragma unroll
  for (int f = 0; f < 2; ++f)
#pragma unroll
    for (int r = 0; r < 4; ++r) {
      float v = l[f][r];
      v += __shfl_xor(v, 1);
      v += __shfl_xor(v, 2);
      v += __shfl_xor(v, 4);
      v += __shfl_xor(v, 8);
      if (lr == 0)
        lse[(size_t)bh * T_ + qbase + f * 16 + lg * 4 + r] = __logf(v);
    }
}

// ---------------- final: out[b,t] = sum_h lse[b,h,t] * cw[h] ----------------
__global__ void proj_out(const float* __restrict__ lse, const float* __restrict__ Wp,
                         float* __restrict__ out) {
  __shared__ float cw[H_];
  int tid = threadIdx.x;
  if (tid < H_) {
    float s = 0.0f;
    for (int g = 0; g < H_; ++g) s += Wp[g * H_ + tid];
    cw[tid] = s;
  }
  __syncthreads();
  int idx = blockIdx.x * blockDim.x + tid;  // b*T + t
  int b = idx >> 11, t = idx & (T_ - 1);
  float s = 0.0f;
#pragma unroll
  for (int h = 0; h < H_; ++h) s += lse[((size_t)(b * H_ + h) * T_) + t] * cw[h];
  out[idx] = s;
}

// ---------------- launch ----------------
extern "C" void kernel_launch(void* const* d_in, const int* in_sizes, int n_in,
                              void* d_out, int out_size, void* d_ws, size_t ws_size,
                              hipStream_t stream) {
  (void)in_sizes; (void)n_in; (void)out_size; (void)ws_size;
  const float* g  = (const float*)d_in[0];   // [B,T,E] fp32
  const float* Wl = (const float*)d_in[1];   // [2E,E] fp32
  const float* Wp = (const float*)d_in[2];   // [H,H] fp32
  float* out = (float*)d_out;                // [B*T] fp32

  char* ws = (char*)d_ws;
  size_t off = 0;
  bf16* g_bf  = (bf16*)(ws + off); off += (size_t)Mtot * K_ * 2;
  bf16* wl_bf = (bf16*)(ws + off); off += (size_t)N2 * K_ * 2;
  bf16* qh    = (bf16*)(ws + off); off += (size_t)B_ * H_ * T_ * D_ * 2;
  bf16* kh    = (bf16*)(ws + off); off += (size_t)B_ * H_ * T_ * D_ * 2;
  float* lse  = (float*)(ws + off);

  cast_f32_to_bf16<<<2048, 256, 0, stream>>>(g,  (ushort*)g_bf,  (Mtot * K_) / 4);
  cast_f32_to_bf16<<<512,  256, 0, stream>>>(Wl, (ushort*)wl_bf, (N2 * K_) / 4);

  lift_gemm<<<dim3(Mtot / BM, N2 / BN), 256, 0, stream>>>(g_bf, wl_bf, qh, kh);

  attn_lse<<<dim3(B_ * H_, T_ / LSE_QT), 256, 0, stream>>>(qh, kh, lse);

  proj_out<<<(B_ * T_) / 256, 256, 0, stream>>>(lse, Wp, out);
}